// Round 1
// 332.093 us; speedup vs baseline: 1.1912x; 1.1912x over previous
//
#include <hip/hip_runtime.h>
#include <hip/hip_bf16.h>

#define BATCH 8
#define CH    256
#define NTOK  4096

typedef __bf16 bf16_t;
typedef __bf16 bf16x8 __attribute__((ext_vector_type(8)));
typedef __bf16 bf16x4 __attribute__((ext_vector_type(4)));
typedef float  fx4    __attribute__((ext_vector_type(4)));

// async global->LDS, 16B per lane, dest = wave-uniform base + lane*16
#define GLOAD_LDS16(gptr, lptr) \
    __builtin_amdgcn_global_load_lds( \
        (const __attribute__((address_space(1))) void*)(gptr), \
        (__attribute__((address_space(3))) void*)(lptr), 16, 0, 0)

// MFMA lane layouts (gfx950, m89/m120-verified):
//   A[m=lane&15][k=quad*8+j], B[k=quad*8+j][n=lane&15], D[row=quad*4+reg][col=lane&15]

// ---------------------------------------------------------------------------
// Projection (unchanged, verified): out[n][d] = sum_c W[d][c]*X[b][c][n] + b[d]
__global__ __launch_bounds__(256, 2) void proj_kernel(
    const float* __restrict__ x, const float* __restrict__ motion,
    const float* __restrict__ wq, const float* __restrict__ bq,
    const float* __restrict__ wk, const float* __restrict__ bk,
    const float* __restrict__ wv, const float* __restrict__ bv,
    bf16_t* __restrict__ qg, bf16_t* __restrict__ kg, bf16_t* __restrict__ vg)
{
    const int mat = blockIdx.y;
    const int b   = blockIdx.x & 7;
    const int n0  = (blockIdx.x >> 3) * 64;
    const float* __restrict__ src  = (mat == 0) ? x  : motion;
    const float* __restrict__ W    = (mat == 0) ? wq : (mat == 1 ? wk : wv);
    const float* __restrict__ bias = (mat == 0) ? bq : (mat == 1 ? bk : bv);

    __shared__ __align__(16) unsigned char smem[55296 + 1024];
    bf16_t* Xt    = (bf16_t*)smem;              // [64][264]  n-major, c contig
    bf16_t* Wl    = (bf16_t*)(smem + 33792);    // [256][40]  d-major, 32c chunk
    bf16_t* OutL  = (bf16_t*)smem;              // [256][72]  reused after GEMM
    float*  biasL = (float*)(smem + 55296);     // [256]

    const int tid  = threadIdx.x;
    const int w    = tid >> 6;
    const int lane = tid & 63;
    const int l16  = lane & 15;
    const int quad = lane >> 4;

    biasL[tid] = bias[tid];

    for (int it = 0; it < 16; ++it) {
        const int c  = it * 16 + (tid >> 4);
        const int j4 = (tid & 15) * 4;
        const float4 v = *(const float4*)&src[((size_t)b * CH + c) * NTOK + n0 + j4];
        Xt[(j4 + 0) * 264 + c] = (bf16_t)v.x;
        Xt[(j4 + 1) * 264 + c] = (bf16_t)v.y;
        Xt[(j4 + 2) * 264 + c] = (bf16_t)v.z;
        Xt[(j4 + 3) * 264 + c] = (bf16_t)v.w;
    }

    fx4 acc[16];
    for (int i = 0; i < 16; ++i) acc[i] = (fx4){0.f, 0.f, 0.f, 0.f};

    for (int cs = 0; cs < 8; ++cs) {
        for (int it = 0; it < 8; ++it) {
            const int d  = it * 32 + (tid >> 3);
            const int c4 = (tid & 7) * 4;
            const float4 v = *(const float4*)&W[(size_t)d * CH + cs * 32 + c4];
            bf16x4 pk;
            pk[0] = (bf16_t)v.x; pk[1] = (bf16_t)v.y;
            pk[2] = (bf16_t)v.z; pk[3] = (bf16_t)v.w;
            *(bf16x4*)&Wl[d * 40 + c4] = pk;
        }
        __syncthreads();
        const bf16x8 af = *(const bf16x8*)&Xt[(w * 16 + l16) * 264 + cs * 32 + quad * 8];
        for (int dp = 0; dp < 16; ++dp) {
            const bf16x8 bf = *(const bf16x8*)&Wl[(dp * 16 + l16) * 40 + quad * 8];
            acc[dp] = __builtin_amdgcn_mfma_f32_16x16x32_bf16(af, bf, acc[dp], 0, 0, 0);
        }
        __syncthreads();
    }

    const float qs = (mat == 0) ? 0.0625f : 1.0f;   // softmax scale folded into Q
    for (int dp = 0; dp < 16; ++dp) {
        const int d = dp * 16 + l16;
        const float bb = biasL[d];
        bf16x4 pk;
        for (int r = 0; r < 4; ++r)
            pk[r] = (bf16_t)((acc[dp][r] + bb) * qs);
        *(bf16x4*)&OutL[d * 72 + w * 16 + quad * 4] = pk;
    }
    __syncthreads();

    if (mat < 2) {
        bf16_t* __restrict__ G = (mat == 0) ? qg : kg;
        for (int it = 0; it < 8; ++it) {
            const int n  = it * 8 + (tid >> 5);
            const int d8 = (tid & 31) * 8;
            bf16x8 vv;
            for (int k = 0; k < 8; ++k) vv[k] = OutL[(d8 + k) * 72 + n];
            *(bf16x8*)&G[((size_t)b * NTOK + n0 + n) * CH + d8] = vv;
        }
    } else {
        for (int it = 0; it < 8; ++it) {
            const int d  = it * 32 + (tid >> 3);
            const int n8 = (tid & 7) * 8;
            const bf16x8 vv = *(const bf16x8*)&OutL[d * 72 + n8];
            *(bf16x8*)&vg[((size_t)b * CH + d) * NTOK + n0 + n8] = vv;
        }
    }
}

// ---------------------------------------------------------------------------
// Attention v2: flash-style, no max-subtraction (logits ~ +-1).
// Block: batch b, i-tile 64. 4 waves with SPLIT roles:
//   QK: wave w -> i-half ih=w&1 (32 rows, Q in regs, 2x16 sub-strips),
//                 j-half jh=w>>1 (16 of 32 j) => each K-frag read feeds 2 MFMAs.
//   PV: wave w -> c-half ch=w&1 (128 ch), i-half is2=w>>1 (32 rows)
//                 => each V-frag read feeds 2 MFMAs; P-frag reused x8.
// Staging: K double-buffered + V single-buffered via global_load_lds issued at
// tile top, drained by the mid-tile barrier (loads fly under QK compute).
// XOR slot swizzles (linear LDS dest + inverse-swizzled global source):
//   K[32][256] rows 512B: phys16Bslot = logslot ^ (j&7)
//   V[256][32] rows  64B: phys16Bslot = logslot ^ (c&3)
// LDS: K0@0 16K | K1@16K | V@32K 16K | P[64][40]@48K+1K 5K | lred[2][64] 512B
__global__ __launch_bounds__(256, 2) void attn_kernel(
    const bf16_t* __restrict__ qg, const bf16_t* __restrict__ kg,
    const bf16_t* __restrict__ vg, float* __restrict__ out)
{
    const int b  = blockIdx.x & 7;     // batch -> XCD locality (round-robin)
    const int i0 = (blockIdx.x >> 3) * 64;

    __shared__ __align__(16) unsigned char smem[54784];
    bf16_t* const K0   = (bf16_t*)smem;               // [32][256] swizzled
    bf16_t* const K1   = (bf16_t*)(smem + 16384);
    bf16_t* const Vb   = (bf16_t*)(smem + 32768);     // [256][32] swizzled
    bf16_t* const P    = (bf16_t*)(smem + 49152);     // [64][40]
    float*  const lred = (float*)(smem + 54272);      // [2][64]

    const int tid  = threadIdx.x;
    const int w    = tid >> 6;
    const int lane = tid & 63;
    const int l16  = lane & 15;
    const int quad = lane >> 4;
    const int ih   = w & 1;      // QK i-half
    const int jh   = w >> 1;     // QK j-half
    const int ch   = w & 1;      // PV c-half
    const int is2  = w >> 1;     // PV i-half
    const int w4   = w * 4;

    // Q A-frags: rows i0 + ih*32 + isub*16 + l16, c = cs*32 + quad*8 + t
    bf16x8 qf[2][8];
    #pragma unroll
    for (int isub = 0; isub < 2; ++isub) {
        const bf16_t* qb = qg + ((size_t)b * NTOK + i0 + ih * 32 + isub * 16 + l16) * CH;
        #pragma unroll
        for (int cs = 0; cs < 8; ++cs)
            qf[isub][cs] = *(const bf16x8*)(qb + cs * 32 + quad * 8);
    }

    fx4 oacc[8][2];
    #pragma unroll
    for (int i = 0; i < 8; ++i) {
        oacc[i][0] = (fx4){0.f, 0.f, 0.f, 0.f};
        oacc[i][1] = (fx4){0.f, 0.f, 0.f, 0.f};
    }
    float rs0[4] = {0.f, 0.f, 0.f, 0.f};
    float rs1[4] = {0.f, 0.f, 0.f, 0.f};

    // hoisted per-lane constants
    const int jrow = jh * 16 + l16;            // K row this lane reads
    const int sxk  = l16 & 7;                  // K read swizzle term
    const int svo  = (quad ^ (l16 & 3)) * 8;   // V read swizzle offset (elems)

    // prologue: stage K tile 0 into K0
    #pragma unroll
    for (int it = 0; it < 4; ++it) {
        const int N   = w4 + it;
        const int kj  = 2 * N + (lane >> 5);
        const int ksl = (lane & 31) ^ (kj & 7);
        GLOAD_LDS16(kg + (((size_t)b * NTOK + kj) << 8) + ksl * 8, K0 + N * 512);
    }
    __syncthreads();

    auto tile = [&](bf16_t* const Kc, bf16_t* const Kn, const int t) {
        const int j0 = t * 32;
        // issue V(t) -> Vb (single buffer; prev readers behind last barrier)
        #pragma unroll
        for (int it = 0; it < 4; ++it) {
            const int N   = w4 + it;
            const int vc  = N * 16 + (lane >> 2);
            const int vsl = (lane & 3) ^ (vc & 3);
            GLOAD_LDS16(vg + (((size_t)b * CH + vc) << 12) + j0 + vsl * 8,
                        Vb + N * 512);
        }
        // issue K(t+1) -> Kn (double buffer)
        if (t + 1 < 128) {
            #pragma unroll
            for (int it = 0; it < 4; ++it) {
                const int N   = w4 + it;
                const int kj  = 2 * N + (lane >> 5);
                const int ksl = (lane & 31) ^ (kj & 7);
                GLOAD_LDS16(kg + (((size_t)b * NTOK + j0 + 32 + kj) << 8) + ksl * 8,
                            Kn + N * 512);
            }
        }

        // QK: S[ih-half 32][jh-half 16]; K-frag reused across both i sub-strips
        fx4 s0 = (fx4){0.f, 0.f, 0.f, 0.f};
        fx4 s1 = (fx4){0.f, 0.f, 0.f, 0.f};
        {
            const bf16_t* krow = Kc + jrow * 256;
            #pragma unroll
            for (int cs = 0; cs < 8; ++cs) {
                const bf16x8 kf = *(const bf16x8*)(krow + (((cs * 4 + quad) ^ sxk) * 8));
                s0 = __builtin_amdgcn_mfma_f32_16x16x32_bf16(qf[0][cs], kf, s0, 0, 0, 0);
                s1 = __builtin_amdgcn_mfma_f32_16x16x32_bf16(qf[1][cs], kf, s1, 0, 0, 0);
            }
        }
        // exp + rowsum partials + P[i][j] write (scale already folded into Q)
        {
            bf16_t* prow = P + (ih * 32 + quad * 4) * 40 + jrow;
            #pragma unroll
            for (int r = 0; r < 4; ++r) {
                const float p0 = __expf(s0[r]);
                const float p1 = __expf(s1[r]);
                rs0[r] += p0;
                rs1[r] += p1;
                prow[r * 40]       = (bf16_t)p0;   // rows ih*32 + quad*4 + r
                prow[r * 40 + 640] = (bf16_t)p1;   // rows +16 (isub=1)
            }
        }
        __syncthreads();   // P visible block-wide; V(t)/K(t+1) DMA drained

        // PV: O[c-half 128][i-half 32] += V * P^T ; V-frag reused across 2 i-strips
        {
            const bf16x8 pf0 = *(const bf16x8*)(P + (is2 * 32 + l16) * 40 + quad * 8);
            const bf16x8 pf1 = *(const bf16x8*)(P + (is2 * 32 + 16 + l16) * 40 + quad * 8);
            const bf16_t* vbase = Vb + (ch * 128 + l16) * 32 + svo;
            #pragma unroll
            for (int cp8 = 0; cp8 < 8; ++cp8) {
                const bf16x8 vf = *(const bf16x8*)(vbase + cp8 * 512);
                oacc[cp8][0] = __builtin_amdgcn_mfma_f32_16x16x32_bf16(vf, pf0, oacc[cp8][0], 0, 0, 0);
                oacc[cp8][1] = __builtin_amdgcn_mfma_f32_16x16x32_bf16(vf, pf1, oacc[cp8][1], 0, 0, 0);
            }
        }
        __syncthreads();   // all reads of P/Vb done -> next tile may overwrite
    };

    #pragma unroll 1
    for (int t = 0; t < 128; t += 2) {
        tile(K0, K1, t);
        tile(K1, K0, t + 1);
    }

    // rowsum: butterfly over the 16 j-lanes, combine jh halves via LDS
    #pragma unroll
    for (int r = 0; r < 4; ++r) {
        float v0 = rs0[r], v1 = rs1[r];
        v0 += __shfl_xor(v0, 1); v0 += __shfl_xor(v0, 2);
        v0 += __shfl_xor(v0, 4); v0 += __shfl_xor(v0, 8);
        v1 += __shfl_xor(v1, 1); v1 += __shfl_xor(v1, 2);
        v1 += __shfl_xor(v1, 4); v1 += __shfl_xor(v1, 8);
        rs0[r] = v0; rs1[r] = v1;
    }
    if (l16 == 0) {
        #pragma unroll
        for (int r = 0; r < 4; ++r) {
            lred[jh * 64 + ih * 32 + quad * 4 + r]      = rs0[r];
            lred[jh * 64 + ih * 32 + 16 + quad * 4 + r] = rs1[r];
        }
    }
    __syncthreads();

    const int   row0  = is2 * 32 + l16;
    const float linv0 = 1.0f / (lred[row0] + lred[64 + row0]);
    const float linv1 = 1.0f / (lred[row0 + 16] + lred[64 + row0 + 16]);

    // O store: c = (ch*8+cp8)*16 + quad*4 + r, i = i0 + is2*32 (+16) + l16
    const size_t obase = (size_t)b * CH * NTOK + i0 + is2 * 32 + l16;
    #pragma unroll
    for (int cp8 = 0; cp8 < 8; ++cp8) {
        const int c0 = (ch * 8 + cp8) * 16 + quad * 4;
        #pragma unroll
        for (int r = 0; r < 4; ++r) {
            out[obase + (size_t)(c0 + r) * NTOK]      = oacc[cp8][0][r] * linv0;
            out[obase + (size_t)(c0 + r) * NTOK + 16] = oacc[cp8][1][r] * linv1;
        }
    }
}

// ---------------------------------------------------------------------------
extern "C" void kernel_launch(void* const* d_in, const int* in_sizes, int n_in,
                              void* d_out, int out_size, void* d_ws, size_t ws_size,
                              hipStream_t stream) {
    const float* x  = (const float*)d_in[0];
    const float* mi = (const float*)d_in[1];
    const float* wq = (const float*)d_in[2];
    const float* bq = (const float*)d_in[3];
    const float* wk = (const float*)d_in[4];
    const float* bk = (const float*)d_in[5];
    const float* wv = (const float*)d_in[6];
    const float* bv = (const float*)d_in[7];

    bf16_t* qg = (bf16_t*)d_ws;
    bf16_t* kg = qg + (size_t)BATCH * NTOK * CH;
    bf16_t* vg = kg + (size_t)BATCH * NTOK * CH;

    dim3 pgrid(BATCH * (NTOK / 64), 3);
    proj_kernel<<<pgrid, 256, 0, stream>>>(x, mi, wq, bq, wk, bk, wv, bv, qg, kg, vg);
    attn_kernel<<<BATCH * (NTOK / 64), 256, 0, stream>>>(qg, kg, vg, (float*)d_out);
}